// Round 1
// baseline (378.516 us; speedup 1.0000x reference)
//
#include <hip/hip_runtime.h>
#include <cmath>

#define NB    128      // batches
#define DIM_  640
#define MM    100      // inner dim (K, unpadded)
#define LDK   136      // LDS row stride in halfs (128 + 8 pad)
#define TFS   68       // f32 transpose-tile row stride in floats (64 + 4 pad)

typedef _Float16 half8 __attribute__((ext_vector_type(8)));
typedef _Float16 half4_t __attribute__((ext_vector_type(4)));
typedef float f32x4 __attribute__((ext_vector_type(4)));

// ---------------------------------------------------------------- prep: d[b,i] = sum_m f16(x)^2 ; also zero rowsum
__global__ __launch_bounds__(256) void prep_d(const float* __restrict__ x,
                                              float* __restrict__ d,
                                              float* __restrict__ rowsum) {
    if (blockIdx.x < (NB * DIM_) / 256)    // 320 blocks zero the 81920-float rowsum
        rowsum[blockIdx.x * 256 + threadIdx.x] = 0.f;
    const int row  = blockIdx.x * 4 + (threadIdx.x >> 6);   // 4 waves/block, 1 row/wave
    const int lane = threadIdx.x & 63;
    const float* xr = x + (size_t)row * MM;
    float a = (float)(_Float16)xr[lane];
    float s = a * a;
    if (lane < MM - 64) {
        float c = (float)(_Float16)xr[64 + lane];
        s += c * c;
    }
    #pragma unroll
    for (int off = 32; off; off >>= 1) s += __shfl_down(s, off, 64);
    if (lane == 0) d[row] = s;
}

// ---------------------------------------------------------------- stage 64 rows of x -> f16 LDS (zero-padded K)
__device__ inline void stage_tile(const float* __restrict__ src,
                                  _Float16* lds, int tid) {
    for (int c = tid; c < 64 * 25; c += 256) {
        const int row = c / 25;
        const int pos = c - row * 25;                 // float4 units
        const float4 v = *(const float4*)(src + (size_t)row * MM + pos * 4);
        half4_t h;
        h.x = (_Float16)v.x; h.y = (_Float16)v.y; h.z = (_Float16)v.z; h.w = (_Float16)v.w;
        *(half4_t*)(&lds[row * LDK + pos * 4]) = h;
    }
    for (int i = tid; i < 64 * 28; i += 256) {        // zero pad k = 100..127
        const int row = i / 28;
        const int k = 100 + (i - row * 28);
        lds[row * LDK + k] = (_Float16)0.f;
    }
}

// ---------------------------------------------------------------- pass 1: sums only. one block per (batch, tile-pair it<=jt)
__global__ __launch_bounds__(256) void bdc_sums(
        const float* __restrict__ x, const float* __restrict__ d,
        const float* __restrict__ t, float* __restrict__ rowsum) {
    __shared__ alignas(16) _Float16 As[64 * LDK];
    __shared__ alignas(16) _Float16 Bs[64 * LDK];
    __shared__ float rowacc[64];
    __shared__ float colacc[64];

    const int b   = blockIdx.y;
    const int p   = blockIdx.x;             // 0..54 -> (it, jt), it <= jt
    int it = 0, rem = p;
    while (rem >= 10 - it) { rem -= 10 - it; ++it; }
    const int jt = it + rem;
    const bool diag = (it == jt);

    const int tid = threadIdx.x;
    const int wave = tid >> 6;
    const int lane = tid & 63;
    const int l16  = lane & 15;
    const int quad = lane >> 4;
    const int rowhalf = wave >> 1;          // 2x2 wave grid over the 64x64 tile
    const int colhalf = wave & 1;

    const float* xb = x + (size_t)b * DIM_ * MM;
    const float* db = d + b * DIM_;

    stage_tile(xb + (size_t)(it * 64) * MM, As, tid);
    if (!diag) stage_tile(xb + (size_t)(jt * 64) * MM, Bs, tid);
    if (tid < 64)  rowacc[tid] = 0.f;
    else if (tid < 128) colacc[tid - 64] = 0.f;

    const float expt = expf(t[0]);
    const int rbase = it * 64 + rowhalf * 32;
    const int cbase = jt * 64 + colhalf * 32;
    float dr[2][4];
    #pragma unroll
    for (int ti = 0; ti < 2; ++ti)
        #pragma unroll
        for (int r = 0; r < 4; ++r)
            dr[ti][r] = db[rbase + ti * 16 + quad * 4 + r];
    const float dcv[2] = { db[cbase + l16], db[cbase + 16 + l16] };

    __syncthreads();

    const _Float16* Bp = diag ? As : Bs;
    f32x4 acc[2][2] = {};
    #pragma unroll
    for (int kk = 0; kk < 4; ++kk) {
        const int k = kk * 32 + quad * 8;
        half8 a0 = *(const half8*)(&As[(rowhalf * 32 + l16) * LDK + k]);
        half8 a1 = *(const half8*)(&As[(rowhalf * 32 + 16 + l16) * LDK + k]);
        half8 b0 = *(const half8*)(&Bp[(colhalf * 32 + l16) * LDK + k]);
        half8 b1 = *(const half8*)(&Bp[(colhalf * 32 + 16 + l16) * LDK + k]);
        acc[0][0] = __builtin_amdgcn_mfma_f32_16x16x32_f16(a0, b0, acc[0][0], 0, 0, 0);
        acc[0][1] = __builtin_amdgcn_mfma_f32_16x16x32_f16(a0, b1, acc[0][1], 0, 0, 0);
        acc[1][0] = __builtin_amdgcn_mfma_f32_16x16x32_f16(a1, b0, acc[1][0], 0, 0, 0);
        acc[1][1] = __builtin_amdgcn_mfma_f32_16x16x32_f16(a1, b1, acc[1][1], 0, 0, 0);
    }

    // ---- epilogue: dcov values -> row/col partial sums only
    float cp0 = 0.f, cp1 = 0.f;
    #pragma unroll
    for (int ti = 0; ti < 2; ++ti) {
        #pragma unroll
        for (int r = 0; r < 4; ++r) {
            const int gi = rbase + ti * 16 + quad * 4 + r;
            float v0, v1;
            {
                const int gj = cbase + l16;
                float raw = dr[ti][r] + dcv[0] - 2.0f * acc[ti][0][r];
                raw = (gi == gj) ? 1e-4f : fmaxf(raw, 1e-4f);
                v0 = sqrtf(expt * raw + 1e-5f);
            }
            {
                const int gj = cbase + 16 + l16;
                float raw = dr[ti][r] + dcv[1] - 2.0f * acc[ti][1][r];
                raw = (gi == gj) ? 1e-4f : fmaxf(raw, 1e-4f);
                v1 = sqrtf(expt * raw + 1e-5f);
            }
            cp0 += v0;
            cp1 += v1;
            float s = v0 + v1;
            s += __shfl_xor(s, 1, 64);
            s += __shfl_xor(s, 2, 64);
            s += __shfl_xor(s, 4, 64);
            s += __shfl_xor(s, 8, 64);
            if (l16 == 0)
                atomicAdd(&rowacc[rowhalf * 32 + ti * 16 + quad * 4 + r], s);
        }
    }
    cp0 += __shfl_xor(cp0, 16, 64); cp0 += __shfl_xor(cp0, 32, 64);
    cp1 += __shfl_xor(cp1, 16, 64); cp1 += __shfl_xor(cp1, 32, 64);
    if (quad == 0) {
        atomicAdd(&colacc[colhalf * 32 + l16],      cp0);
        atomicAdd(&colacc[colhalf * 32 + 16 + l16], cp1);
    }

    __syncthreads();

    if (tid < 64) {
        atomicAdd(&rowsum[b * DIM_ + it * 64 + tid], rowacc[tid]);
        if (!diag) atomicAdd(&rowsum[b * DIM_ + jt * 64 + tid], colacc[tid]);
    }
}

// ---------------------------------------------------------------- per-batch means
__global__ __launch_bounds__(256) void bdc_tot(const float* __restrict__ rowsum,
                                               float* __restrict__ rm,
                                               float* __restrict__ tot) {
    const int b = blockIdx.x, tid = threadIdx.x;
    const float* rs = rowsum + b * DIM_;
    const float v0 = rs[tid];
    const float v1 = rs[tid + 256];
    const float v2 = (tid < 128) ? rs[tid + 512] : 0.f;
    __shared__ float red[256];
    red[tid] = v0 + v1 + v2;
    __syncthreads();
    for (int off = 128; off; off >>= 1) {
        if (tid < off) red[tid] += red[tid + off];
        __syncthreads();
    }
    const float inv = 1.0f / 640.0f;
    rm[b * DIM_ + tid]       = v0 * inv;
    rm[b * DIM_ + 256 + tid] = v1 * inv;
    if (tid < 128) rm[b * DIM_ + 512 + tid] = v2 * inv;
    if (tid == 0) tot[b] = red[0] / (640.0f * 640.0f);
}

// ---------------------------------------------------------------- pass 3: recompute dcov tile, center, store f32 coalesced
// grid (100, NB): one block per (batch, it, jt) -- full tile grid, no symmetry
__global__ __launch_bounds__(256) void bdc_out(
        const float* __restrict__ x, const float* __restrict__ d,
        const float* __restrict__ t, const float* __restrict__ rm,
        const float* __restrict__ tot, float* __restrict__ out) {
    __shared__ alignas(16) _Float16 As[64 * LDK];
    __shared__ alignas(16) _Float16 Bs[64 * LDK];
    float* Tf = (float*)As;                 // 64*TFS*4 = 17408 B == sizeof(As); As dead after MFMA

    const int b  = blockIdx.y;
    const int it = blockIdx.x / 10;
    const int jt = blockIdx.x - it * 10;
    const bool diag = (it == jt);

    const int tid = threadIdx.x;
    const int wave = tid >> 6;
    const int lane = tid & 63;
    const int l16  = lane & 15;
    const int quad = lane >> 4;
    const int rowhalf = wave >> 1;
    const int colhalf = wave & 1;

    const float* xb  = x + (size_t)b * DIM_ * MM;
    const float* db  = d + b * DIM_;
    const float* rmb = rm + b * DIM_;

    stage_tile(xb + (size_t)(it * 64) * MM, As, tid);
    if (!diag) stage_tile(xb + (size_t)(jt * 64) * MM, Bs, tid);

    const float expt = expf(t[0]);
    const float cb   = tot[b];
    const int rbase = it * 64 + rowhalf * 32;
    const int cbase = jt * 64 + colhalf * 32;
    float dr[2][4], rr[2][4];
    #pragma unroll
    for (int ti = 0; ti < 2; ++ti)
        #pragma unroll
        for (int r = 0; r < 4; ++r) {
            const int gi = rbase + ti * 16 + quad * 4 + r;
            dr[ti][r] = db[gi];
            rr[ti][r] = rmb[gi];
        }
    const float dcv[2] = { db[cbase + l16],  db[cbase + 16 + l16] };
    const float rc[2]  = { rmb[cbase + l16], rmb[cbase + 16 + l16] };

    __syncthreads();

    const _Float16* Bp = diag ? As : Bs;
    f32x4 acc[2][2] = {};
    #pragma unroll
    for (int kk = 0; kk < 4; ++kk) {
        const int k = kk * 32 + quad * 8;
        half8 a0 = *(const half8*)(&As[(rowhalf * 32 + l16) * LDK + k]);
        half8 a1 = *(const half8*)(&As[(rowhalf * 32 + 16 + l16) * LDK + k]);
        half8 b0 = *(const half8*)(&Bp[(colhalf * 32 + l16) * LDK + k]);
        half8 b1 = *(const half8*)(&Bp[(colhalf * 32 + 16 + l16) * LDK + k]);
        acc[0][0] = __builtin_amdgcn_mfma_f32_16x16x32_f16(a0, b0, acc[0][0], 0, 0, 0);
        acc[0][1] = __builtin_amdgcn_mfma_f32_16x16x32_f16(a0, b1, acc[0][1], 0, 0, 0);
        acc[1][0] = __builtin_amdgcn_mfma_f32_16x16x32_f16(a1, b0, acc[1][0], 0, 0, 0);
        acc[1][1] = __builtin_amdgcn_mfma_f32_16x16x32_f16(a1, b1, acc[1][1], 0, 0, 0);
    }

    // ---- epilogue: dcov + centering, all in registers
    float o[2][4][2];
    #pragma unroll
    for (int ti = 0; ti < 2; ++ti)
        #pragma unroll
        for (int r = 0; r < 4; ++r) {
            const int gi = rbase + ti * 16 + quad * 4 + r;
            const float rowterm = cb - rr[ti][r];
            #pragma unroll
            for (int tj = 0; tj < 2; ++tj) {
                const int gj = cbase + tj * 16 + l16;
                float raw = dr[ti][r] + dcv[tj] - 2.0f * acc[ti][tj][r];
                raw = (gi == gj) ? 1e-4f : fmaxf(raw, 1e-4f);
                o[ti][r][tj] = sqrtf(expt * raw + 1e-5f) + rowterm - rc[tj];
            }
        }

    __syncthreads();   // all As/Bs fragment reads done -> Tf may overwrite As

    #pragma unroll
    for (int ti = 0; ti < 2; ++ti)
        #pragma unroll
        for (int r = 0; r < 4; ++r) {
            const int ri = rowhalf * 32 + ti * 16 + quad * 4 + r;
            Tf[ri * TFS + colhalf * 32 + l16]      = o[ti][r][0];
            Tf[ri * TFS + colhalf * 32 + 16 + l16] = o[ti][r][1];
        }

    __syncthreads();

    // ---- coalesced float4 stores: wave writes 4 rows x 64B, block covers 64x64 tile
    float* ob = out + ((size_t)(b * DIM_ + it * 64)) * DIM_ + jt * 64;
    #pragma unroll
    for (int w = tid; w < 1024; w += 256) {
        const int r2 = w >> 4;
        const int c4 = (w & 15) * 4;
        const f32x4 v = *(const f32x4*)(&Tf[r2 * TFS + c4]);
        *(f32x4*)(ob + (size_t)r2 * DIM_ + c4) = v;
    }
}

// ---------------------------------------------------------------- launch
extern "C" void kernel_launch(void* const* d_in, const int* in_sizes, int n_in,
                              void* d_out, int out_size, void* d_ws, size_t ws_size,
                              hipStream_t stream) {
    const float* x = (const float*)d_in[0];
    const float* t = (const float*)d_in[1];
    float* out = (float*)d_out;

    char* ws = (char*)d_ws;
    float* d      = (float*)(ws);                      // 327,680 B
    float* rowsum = (float*)(ws + 327680);             // 327,680 B
    float* rm     = (float*)(ws + 2 * 327680);         // 327,680 B
    float* tot    = (float*)(ws + 3 * 327680);         // 512 B

    prep_d<<<dim3((NB * DIM_) / 4), dim3(256), 0, stream>>>(x, d, rowsum);
    bdc_sums<<<dim3(55, NB), dim3(256), 0, stream>>>(x, d, t, rowsum);
    bdc_tot<<<dim3(NB), dim3(256), 0, stream>>>(rowsum, rm, tot);
    bdc_out<<<dim3(100, NB), dim3(256), 0, stream>>>(x, d, t, rm, tot, out);
}

// Round 2
// 304.583 us; speedup vs baseline: 1.2427x; 1.2427x over previous
//
#include <hip/hip_runtime.h>
#include <cmath>

#define NB    128      // batches
#define DIM_  640
#define MM    100      // inner dim (K, unpadded)
#define LDK   136      // f16 staging LDS row stride in halfs (128 + 8 pad)
#define TS    72       // f16 store-transpose tile row stride in halfs
#define TTS   68       // f32 mirror-transpose tile row stride in floats (even -> 16B aligned rows)

typedef _Float16 half8 __attribute__((ext_vector_type(8)));
typedef _Float16 half4_t __attribute__((ext_vector_type(4)));
typedef float f32x4 __attribute__((ext_vector_type(4)));

// stage 64 rows of x -> f16 LDS (zero-padded to K=128) and compute per-row d = sum f16(x)^2
// thread t: row = t>>2, sub-lane = t&3; each row's 25 float4-chunks split 7/6/6/6 across sub-lanes
__device__ inline void stage_tile_d(const float* __restrict__ src,
                                    _Float16* __restrict__ lds,
                                    float* __restrict__ dsrow, int tid) {
    const int row = tid >> 2;              // 0..63
    const int sub = tid & 3;
    const float* sr = src + (size_t)row * MM + sub * 4;
    _Float16* lr = lds + row * LDK + sub * 4;
    float acc = 0.f;
    #pragma unroll
    for (int k = 0; k < 6; ++k) {          // chunks sub + 4k, k=0..5 (all sub-lanes)
        const float4 v = *(const float4*)(sr + 16 * k);
        half4_t h;
        h.x = (_Float16)v.x; h.y = (_Float16)v.y;
        h.z = (_Float16)v.z; h.w = (_Float16)v.w;
        *(half4_t*)(lr + 16 * k) = h;
        const float a0 = (float)h.x, a1 = (float)h.y,
                    a2 = (float)h.z, a3 = (float)h.w;
        acc += a0 * a0 + a1 * a1 + a2 * a2 + a3 * a3;
    }
    if (sub == 0) {                        // chunk 24 (floats 96..99)
        const float4 v = *(const float4*)(sr + 96);
        half4_t h;
        h.x = (_Float16)v.x; h.y = (_Float16)v.y;
        h.z = (_Float16)v.z; h.w = (_Float16)v.w;
        *(half4_t*)(lr + 96) = h;
        const float a0 = (float)h.x, a1 = (float)h.y,
                    a2 = (float)h.z, a3 = (float)h.w;
        acc += a0 * a0 + a1 * a1 + a2 * a2 + a3 * a3;
    }
    acc += __shfl_xor(acc, 1, 64);
    acc += __shfl_xor(acc, 2, 64);
    if (sub == 0) dsrow[row] = acc;
    // zero pad k = 100..127 (7 half4 per row)
    const float2 z2 = make_float2(0.f, 0.f);
    for (int i = tid; i < 64 * 7; i += 256) {
        const int r = i / 7;
        const int c = 100 + (i - r * 7) * 4;
        *(float2*)(&lds[r * LDK + c]) = z2;
    }
}

// ---------------------------------------------------------------- pass 1: one block per (batch, tile-pair it<=jt)
// computes 64x64 dcov tile once, stores f16 tile (tile-linear, upper triangle only),
// writes per-slot row-sum partials (no atomics, no zero-init needed)
__global__ __launch_bounds__(256) void bdc_pass1(
        const float* __restrict__ x, const float* __restrict__ t,
        float* __restrict__ r2, _Float16* __restrict__ dc) {
    __shared__ alignas(16) _Float16 As[64 * LDK];
    __shared__ alignas(16) _Float16 Bs[64 * LDK];
    __shared__ float rowacc[64];
    __shared__ float colacc[64];
    __shared__ float dsi[64];
    __shared__ float dsj[64];
    _Float16* T = As;                       // f16 store-staging tile aliases As (dead after MFMA)

    const int b   = blockIdx.y;
    const int p   = blockIdx.x;             // 0..54 -> (it, jt), it <= jt
    int it = 0, rem = p;
    while (rem >= 10 - it) { rem -= 10 - it; ++it; }
    const int jt = it + rem;
    const bool diag = (it == jt);

    const int tid = threadIdx.x;
    const int wave = tid >> 6;
    const int lane = tid & 63;
    const int l16  = lane & 15;
    const int quad = lane >> 4;
    const int rowhalf = wave >> 1;          // 2x2 wave grid over the 64x64 tile
    const int colhalf = wave & 1;

    if (tid < 64)  rowacc[tid] = 0.f;
    else if (tid < 128) colacc[tid - 64] = 0.f;

    const float* xb = x + (size_t)b * DIM_ * MM;
    stage_tile_d(xb + (size_t)(it * 64) * MM, As, dsi, tid);
    if (!diag) stage_tile_d(xb + (size_t)(jt * 64) * MM, Bs, dsj, tid);

    const float expt = expf(t[0]);

    __syncthreads();

    const float* dsjp = diag ? dsi : dsj;
    float dr[2][4];
    #pragma unroll
    for (int ti = 0; ti < 2; ++ti)
        #pragma unroll
        for (int r = 0; r < 4; ++r)
            dr[ti][r] = dsi[rowhalf * 32 + ti * 16 + quad * 4 + r];
    const float dcv[2] = { dsjp[colhalf * 32 + l16], dsjp[colhalf * 32 + 16 + l16] };

    const int rbase = it * 64 + rowhalf * 32;
    const int cbase = jt * 64 + colhalf * 32;

    const _Float16* Bp = diag ? As : Bs;
    f32x4 acc[2][2] = {};
    #pragma unroll
    for (int kk = 0; kk < 4; ++kk) {
        const int k = kk * 32 + quad * 8;
        half8 a0 = *(const half8*)(&As[(rowhalf * 32 + l16) * LDK + k]);
        half8 a1 = *(const half8*)(&As[(rowhalf * 32 + 16 + l16) * LDK + k]);
        half8 b0 = *(const half8*)(&Bp[(colhalf * 32 + l16) * LDK + k]);
        half8 b1 = *(const half8*)(&Bp[(colhalf * 32 + 16 + l16) * LDK + k]);
        acc[0][0] = __builtin_amdgcn_mfma_f32_16x16x32_f16(a0, b0, acc[0][0], 0, 0, 0);
        acc[0][1] = __builtin_amdgcn_mfma_f32_16x16x32_f16(a0, b1, acc[0][1], 0, 0, 0);
        acc[1][0] = __builtin_amdgcn_mfma_f32_16x16x32_f16(a1, b0, acc[1][0], 0, 0, 0);
        acc[1][1] = __builtin_amdgcn_mfma_f32_16x16x32_f16(a1, b1, acc[1][1], 0, 0, 0);
    }

    // ---- epilogue: dcov values + row/col partial sums
    float v[2][4][2];
    float cp0 = 0.f, cp1 = 0.f;
    #pragma unroll
    for (int ti = 0; ti < 2; ++ti) {
        #pragma unroll
        for (int r = 0; r < 4; ++r) {
            const int gi = rbase + ti * 16 + quad * 4 + r;
            #pragma unroll
            for (int tj = 0; tj < 2; ++tj) {
                const int gj = cbase + tj * 16 + l16;
                float raw = dr[ti][r] + dcv[tj] - 2.0f * acc[ti][tj][r];
                raw = (gi == gj) ? 1e-4f : fmaxf(raw, 1e-4f);
                v[ti][r][tj] = sqrtf(expt * raw + 1e-5f);
            }
            cp0 += v[ti][r][0];
            cp1 += v[ti][r][1];
            float s = v[ti][r][0] + v[ti][r][1];
            s += __shfl_xor(s, 1, 64);
            s += __shfl_xor(s, 2, 64);
            s += __shfl_xor(s, 4, 64);
            s += __shfl_xor(s, 8, 64);
            if (l16 == 0)
                atomicAdd(&rowacc[rowhalf * 32 + ti * 16 + quad * 4 + r], s);
        }
    }
    cp0 += __shfl_xor(cp0, 16, 64); cp0 += __shfl_xor(cp0, 32, 64);
    cp1 += __shfl_xor(cp1, 16, 64); cp1 += __shfl_xor(cp1, 32, 64);
    if (quad == 0) {
        atomicAdd(&colacc[colhalf * 32 + l16],      cp0);
        atomicAdd(&colacc[colhalf * 32 + 16 + l16], cp1);
    }

    __syncthreads();   // all As/Bs fragment reads done -> T may overwrite As

    #pragma unroll
    for (int ti = 0; ti < 2; ++ti)
        #pragma unroll
        for (int r = 0; r < 4; ++r) {
            const int ri = rowhalf * 32 + ti * 16 + quad * 4 + r;
            T[ri * TS + colhalf * 32 + l16]      = (_Float16)v[ti][r][0];
            T[ri * TS + colhalf * 32 + 16 + l16] = (_Float16)v[ti][r][1];
        }

    __syncthreads();

    // ---- coalesced tile-linear store (upper triangle only, no transposed gather)
    _Float16* dcT = dc + ((size_t)(b * 55 + p)) * 4096;
    #pragma unroll
    for (int w = tid; w < 512; w += 256) {
        const int r2i = w >> 3;
        const int c2  = (w & 7) * 8;
        *(half8*)(dcT + r2i * 64 + c2) = *(const half8*)(&T[r2i * TS + c2]);
    }

    // ---- per-slot rowsum partials: each (slot,row) written by exactly one block
    if (tid < 64) {
        r2[((size_t)b * 10 + jt) * DIM_ + it * 64 + tid] = rowacc[tid];
        if (!diag)
            r2[((size_t)b * 10 + it) * DIM_ + jt * 64 + tid] = colacc[tid];
    }
}

// ---------------------------------------------------------------- pass 2: read f16 tile, center, store f32
// one block per (batch, tile-pair it<=jt); writes direct tile + mirrored tile via f32 LDS transpose
__global__ __launch_bounds__(256) void bdc_center(
        const _Float16* __restrict__ dc, const float* __restrict__ r2,
        float* __restrict__ out) {
    __shared__ alignas(16) float Tt[64 * TTS];
    __shared__ float rm_s[DIM_];
    __shared__ float wred[4];

    const int b = blockIdx.y;
    const int p = blockIdx.x;
    int it = 0, rem = p;
    while (rem >= 10 - it) { rem -= 10 - it; ++it; }
    const int jt = it + rem;
    const bool diag = (it == jt);

    const int tid  = threadIdx.x;
    const int lane = tid & 63;
    const int wave = tid >> 6;

    // ---- per-block row means + total mean from the slot table (L2-cached, overlapped)
    const float* rb = r2 + (size_t)b * 10 * DIM_;
    float tpart = 0.f;
    for (int i = tid; i < DIM_; i += 256) {
        float s = 0.f;
        #pragma unroll
        for (int ss = 0; ss < 10; ++ss) s += rb[ss * DIM_ + i];
        rm_s[i] = s * (1.0f / 640.0f);
        tpart += s;
    }
    #pragma unroll
    for (int off = 32; off; off >>= 1) tpart += __shfl_xor(tpart, off, 64);
    if (lane == 0) wred[wave] = tpart;
    __syncthreads();
    const float tot = (wred[0] + wred[1] + wred[2] + wred[3]) * (1.0f / 409600.0f);

    const _Float16* dcT = dc + ((size_t)(b * 55 + p)) * 4096;
    float* ob = out + (size_t)b * DIM_ * DIM_;

    #pragma unroll
    for (int k2 = 0; k2 < 2; ++k2) {
        const int w  = tid + k2 * 256;
        const int r  = w >> 3;
        const int c8 = (w & 7) * 8;
        const half8 h = *(const half8*)(dcT + r * 64 + c8);
        const float ci = tot - rm_s[it * 64 + r];
        float o[8];
        #pragma unroll
        for (int k = 0; k < 8; ++k)
            o[k] = (float)h[k] - rm_s[jt * 64 + c8 + k] + ci;
        f32x4 o0 = { o[0], o[1], o[2], o[3] };
        f32x4 o1 = { o[4], o[5], o[6], o[7] };
        f32x4* op = (f32x4*)(ob + (size_t)(it * 64 + r) * DIM_ + jt * 64 + c8);
        op[0] = o0; op[1] = o1;
        if (!diag) {
            #pragma unroll
            for (int k = 0; k < 8; ++k)
                Tt[(c8 + k) * TTS + r] = o[k];      // transposed scatter (centered value is symmetric)
        }
    }

    if (!diag) {
        __syncthreads();
        #pragma unroll
        for (int k4 = 0; k4 < 4; ++k4) {
            const int u  = tid + k4 * 256;
            const int rr = u >> 4;
            const int c4 = (u & 15) * 4;
            const f32x4 vv = *(const f32x4*)(&Tt[rr * TTS + c4]);
            *(f32x4*)(ob + (size_t)(jt * 64 + rr) * DIM_ + it * 64 + c4) = vv;
        }
    }
}

// ---------------------------------------------------------------- launch: TWO kernels, no pre-stages
extern "C" void kernel_launch(void* const* d_in, const int* in_sizes, int n_in,
                              void* d_out, int out_size, void* d_ws, size_t ws_size,
                              hipStream_t stream) {
    const float* x = (const float*)d_in[0];
    const float* t = (const float*)d_in[1];
    float* out = (float*)d_out;

    char* ws = (char*)d_ws;
    float*    r2 = (float*)ws;                      // 128*10*640*4 = 3,276,800 B
    _Float16* dc = (_Float16*)(ws + 3276800);       // 128*55*4096*2 = 57,671,680 B

    bdc_pass1<<<dim3(55, NB), dim3(256), 0, stream>>>(x, t, r2, dc);
    bdc_center<<<dim3(55, NB), dim3(256), 0, stream>>>(dc, r2, out);
}

// Round 3
// 289.542 us; speedup vs baseline: 1.3073x; 1.0519x over previous
//
#include <hip/hip_runtime.h>
#include <cmath>

#define NB    128      // batches
#define DIM_  640
#define MM    100      // inner dim (K, unpadded)
#define LDK   136      // f16 staging LDS row stride in halfs (128 + 8 pad)
#define TS    72       // f16 store-transpose tile row stride in halfs
#define TTS   68       // f32 mirror-transpose tile row stride in floats (even -> 16B aligned rows)

#define NWG   (NB * 55)   // 7040 total blocks; 7040 % 8 == 0 -> simple XCD swizzle is bijective
#define CPX   (NWG / 8)   // 880 blocks per XCD chunk = 16 whole batches

typedef _Float16 half8 __attribute__((ext_vector_type(8)));
typedef _Float16 half4_t __attribute__((ext_vector_type(4)));
typedef float f32x4 __attribute__((ext_vector_type(4)));

// XCD-aware bijective block swizzle: all 55 blocks of a batch (and 16 consecutive
// batches) land on ONE XCD -> x-slice + dc tiles stay in that XCD's private L2.
__device__ inline void decode_bp(int bid, int& b, int& p) {
    const int dec = (bid & 7) * CPX + (bid >> 3);
    b = dec / 55;
    p = dec - b * 55;
}

// stage 64 rows of x -> f16 LDS (zero-padded to K=128) and compute per-row d = sum f16(x)^2
// thread t: row = t>>2, sub-lane = t&3; each row's 25 float4-chunks split 7/6/6/6 across sub-lanes
__device__ inline void stage_tile_d(const float* __restrict__ src,
                                    _Float16* __restrict__ lds,
                                    float* __restrict__ dsrow, int tid) {
    const int row = tid >> 2;              // 0..63
    const int sub = tid & 3;
    const float* sr = src + (size_t)row * MM + sub * 4;
    _Float16* lr = lds + row * LDK + sub * 4;
    float acc = 0.f;
    #pragma unroll
    for (int k = 0; k < 6; ++k) {          // chunks sub + 4k, k=0..5 (all sub-lanes)
        const float4 v = *(const float4*)(sr + 16 * k);
        half4_t h;
        h.x = (_Float16)v.x; h.y = (_Float16)v.y;
        h.z = (_Float16)v.z; h.w = (_Float16)v.w;
        *(half4_t*)(lr + 16 * k) = h;
        const float a0 = (float)h.x, a1 = (float)h.y,
                    a2 = (float)h.z, a3 = (float)h.w;
        acc += a0 * a0 + a1 * a1 + a2 * a2 + a3 * a3;
    }
    if (sub == 0) {                        // chunk 24 (floats 96..99)
        const float4 v = *(const float4*)(sr + 96);
        half4_t h;
        h.x = (_Float16)v.x; h.y = (_Float16)v.y;
        h.z = (_Float16)v.z; h.w = (_Float16)v.w;
        *(half4_t*)(lr + 96) = h;
        const float a0 = (float)h.x, a1 = (float)h.y,
                    a2 = (float)h.z, a3 = (float)h.w;
        acc += a0 * a0 + a1 * a1 + a2 * a2 + a3 * a3;
    }
    acc += __shfl_xor(acc, 1, 64);
    acc += __shfl_xor(acc, 2, 64);
    if (sub == 0) dsrow[row] = acc;
    // zero pad k = 100..127 (7 half4 per row)
    const float2 z2 = make_float2(0.f, 0.f);
    for (int i = tid; i < 64 * 7; i += 256) {
        const int r = i / 7;
        const int c = 100 + (i - r * 7) * 4;
        *(float2*)(&lds[r * LDK + c]) = z2;
    }
}

// ---------------------------------------------------------------- pass 1: one block per (batch, tile-pair it<=jt)
// computes 64x64 dcov tile once, stores f16 tile (tile-linear, upper triangle only),
// writes per-slot row-sum partials (no atomics, no zero-init needed)
__global__ __launch_bounds__(256) void bdc_pass1(
        const float* __restrict__ x, const float* __restrict__ t,
        float* __restrict__ r2, _Float16* __restrict__ dc) {
    __shared__ alignas(16) _Float16 As[64 * LDK];
    __shared__ alignas(16) _Float16 Bs[64 * LDK];
    __shared__ float rowacc[64];
    __shared__ float colacc[64];
    __shared__ float dsi[64];
    __shared__ float dsj[64];
    _Float16* T = As;                       // f16 store-staging tile aliases As (dead after MFMA)

    int b, p;
    decode_bp(blockIdx.x, b, p);            // 0..54 -> (it, jt), it <= jt
    int it = 0, rem = p;
    while (rem >= 10 - it) { rem -= 10 - it; ++it; }
    const int jt = it + rem;
    const bool diag = (it == jt);

    const int tid = threadIdx.x;
    const int wave = tid >> 6;
    const int lane = tid & 63;
    const int l16  = lane & 15;
    const int quad = lane >> 4;
    const int rowhalf = wave >> 1;          // 2x2 wave grid over the 64x64 tile
    const int colhalf = wave & 1;

    if (tid < 64)  rowacc[tid] = 0.f;
    else if (tid < 128) colacc[tid - 64] = 0.f;

    const float* xb = x + (size_t)b * DIM_ * MM;
    stage_tile_d(xb + (size_t)(it * 64) * MM, As, dsi, tid);
    if (!diag) stage_tile_d(xb + (size_t)(jt * 64) * MM, Bs, dsj, tid);

    const float expt = expf(t[0]);

    __syncthreads();

    const float* dsjp = diag ? dsi : dsj;
    float dr[2][4];
    #pragma unroll
    for (int ti = 0; ti < 2; ++ti)
        #pragma unroll
        for (int r = 0; r < 4; ++r)
            dr[ti][r] = dsi[rowhalf * 32 + ti * 16 + quad * 4 + r];
    const float dcv[2] = { dsjp[colhalf * 32 + l16], dsjp[colhalf * 32 + 16 + l16] };

    const int rbase = it * 64 + rowhalf * 32;
    const int cbase = jt * 64 + colhalf * 32;

    const _Float16* Bp = diag ? As : Bs;
    f32x4 acc[2][2] = {};
    #pragma unroll
    for (int kk = 0; kk < 4; ++kk) {
        const int k = kk * 32 + quad * 8;
        half8 a0 = *(const half8*)(&As[(rowhalf * 32 + l16) * LDK + k]);
        half8 a1 = *(const half8*)(&As[(rowhalf * 32 + 16 + l16) * LDK + k]);
        half8 b0 = *(const half8*)(&Bp[(colhalf * 32 + l16) * LDK + k]);
        half8 b1 = *(const half8*)(&Bp[(colhalf * 32 + 16 + l16) * LDK + k]);
        acc[0][0] = __builtin_amdgcn_mfma_f32_16x16x32_f16(a0, b0, acc[0][0], 0, 0, 0);
        acc[0][1] = __builtin_amdgcn_mfma_f32_16x16x32_f16(a0, b1, acc[0][1], 0, 0, 0);
        acc[1][0] = __builtin_amdgcn_mfma_f32_16x16x32_f16(a1, b0, acc[1][0], 0, 0, 0);
        acc[1][1] = __builtin_amdgcn_mfma_f32_16x16x32_f16(a1, b1, acc[1][1], 0, 0, 0);
    }

    // ---- epilogue: dcov values + row/col partial sums
    float v[2][4][2];
    float cp0 = 0.f, cp1 = 0.f;
    #pragma unroll
    for (int ti = 0; ti < 2; ++ti) {
        #pragma unroll
        for (int r = 0; r < 4; ++r) {
            const int gi = rbase + ti * 16 + quad * 4 + r;
            #pragma unroll
            for (int tj = 0; tj < 2; ++tj) {
                const int gj = cbase + tj * 16 + l16;
                float raw = dr[ti][r] + dcv[tj] - 2.0f * acc[ti][tj][r];
                raw = (gi == gj) ? 1e-4f : fmaxf(raw, 1e-4f);
                v[ti][r][tj] = sqrtf(expt * raw + 1e-5f);
            }
            cp0 += v[ti][r][0];
            cp1 += v[ti][r][1];
            float s = v[ti][r][0] + v[ti][r][1];
            s += __shfl_xor(s, 1, 64);
            s += __shfl_xor(s, 2, 64);
            s += __shfl_xor(s, 4, 64);
            s += __shfl_xor(s, 8, 64);
            if (l16 == 0)
                atomicAdd(&rowacc[rowhalf * 32 + ti * 16 + quad * 4 + r], s);
        }
    }
    cp0 += __shfl_xor(cp0, 16, 64); cp0 += __shfl_xor(cp0, 32, 64);
    cp1 += __shfl_xor(cp1, 16, 64); cp1 += __shfl_xor(cp1, 32, 64);
    if (quad == 0) {
        atomicAdd(&colacc[colhalf * 32 + l16],      cp0);
        atomicAdd(&colacc[colhalf * 32 + 16 + l16], cp1);
    }

    __syncthreads();   // all As/Bs fragment reads done -> T may overwrite As

    #pragma unroll
    for (int ti = 0; ti < 2; ++ti)
        #pragma unroll
        for (int r = 0; r < 4; ++r) {
            const int ri = rowhalf * 32 + ti * 16 + quad * 4 + r;
            T[ri * TS + colhalf * 32 + l16]      = (_Float16)v[ti][r][0];
            T[ri * TS + colhalf * 32 + 16 + l16] = (_Float16)v[ti][r][1];
        }

    __syncthreads();

    // ---- coalesced tile-linear store (upper triangle only, no transposed gather)
    _Float16* dcT = dc + ((size_t)(b * 55 + p)) * 4096;
    #pragma unroll
    for (int w = tid; w < 512; w += 256) {
        const int r2i = w >> 3;
        const int c2  = (w & 7) * 8;
        *(half8*)(dcT + r2i * 64 + c2) = *(const half8*)(&T[r2i * TS + c2]);
    }

    // ---- per-slot rowsum partials: each (slot,row) written by exactly one block
    if (tid < 64) {
        r2[((size_t)b * 10 + jt) * DIM_ + it * 64 + tid] = rowacc[tid];
        if (!diag)
            r2[((size_t)b * 10 + it) * DIM_ + jt * 64 + tid] = colacc[tid];
    }
}

// ---------------------------------------------------------------- pass 2: read f16 tile, center, store f32
// one block per (batch, tile-pair it<=jt); writes direct tile + mirrored tile via f32 LDS transpose
__global__ __launch_bounds__(256) void bdc_center(
        const _Float16* __restrict__ dc, const float* __restrict__ r2,
        float* __restrict__ out) {
    __shared__ alignas(16) float Tt[64 * TTS];
    __shared__ float rm_s[DIM_];
    __shared__ float wred[4];

    int b, p;
    decode_bp(blockIdx.x, b, p);            // same swizzle as pass1 -> same-XCD dc/r2 locality
    int it = 0, rem = p;
    while (rem >= 10 - it) { rem -= 10 - it; ++it; }
    const int jt = it + rem;
    const bool diag = (it == jt);

    const int tid  = threadIdx.x;
    const int lane = tid & 63;
    const int wave = tid >> 6;

    // ---- per-block row means + total mean from the slot table (L2-cached, overlapped)
    const float* rb = r2 + (size_t)b * 10 * DIM_;
    float tpart = 0.f;
    for (int i = tid; i < DIM_; i += 256) {
        float s = 0.f;
        #pragma unroll
        for (int ss = 0; ss < 10; ++ss) s += rb[ss * DIM_ + i];
        rm_s[i] = s * (1.0f / 640.0f);
        tpart += s;
    }
    #pragma unroll
    for (int off = 32; off; off >>= 1) tpart += __shfl_xor(tpart, off, 64);
    if (lane == 0) wred[wave] = tpart;
    __syncthreads();
    const float tot = (wred[0] + wred[1] + wred[2] + wred[3]) * (1.0f / 409600.0f);

    const _Float16* dcT = dc + ((size_t)(b * 55 + p)) * 4096;
    float* ob = out + (size_t)b * DIM_ * DIM_;

    #pragma unroll
    for (int k2 = 0; k2 < 2; ++k2) {
        const int w  = tid + k2 * 256;
        const int r  = w >> 3;
        const int c8 = (w & 7) * 8;
        const half8 h = *(const half8*)(dcT + r * 64 + c8);
        const float ci = tot - rm_s[it * 64 + r];
        float o[8];
        #pragma unroll
        for (int k = 0; k < 8; ++k)
            o[k] = (float)h[k] - rm_s[jt * 64 + c8 + k] + ci;
        f32x4 o0 = { o[0], o[1], o[2], o[3] };
        f32x4 o1 = { o[4], o[5], o[6], o[7] };
        f32x4* op = (f32x4*)(ob + (size_t)(it * 64 + r) * DIM_ + jt * 64 + c8);
        op[0] = o0; op[1] = o1;
        if (!diag) {
            #pragma unroll
            for (int k = 0; k < 8; ++k)
                Tt[(c8 + k) * TTS + r] = o[k];      // transposed scatter (centered value is symmetric)
        }
    }

    if (!diag) {
        __syncthreads();
        #pragma unroll
        for (int k4 = 0; k4 < 4; ++k4) {
            const int u  = tid + k4 * 256;
            const int rr = u >> 4;
            const int c4 = (u & 15) * 4;
            const f32x4 vv = *(const f32x4*)(&Tt[rr * TTS + c4]);
            *(f32x4*)(ob + (size_t)(jt * 64 + rr) * DIM_ + it * 64 + c4) = vv;
        }
    }
}

// ---------------------------------------------------------------- launch: TWO kernels, no pre-stages
extern "C" void kernel_launch(void* const* d_in, const int* in_sizes, int n_in,
                              void* d_out, int out_size, void* d_ws, size_t ws_size,
                              hipStream_t stream) {
    const float* x = (const float*)d_in[0];
    const float* t = (const float*)d_in[1];
    float* out = (float*)d_out;

    char* ws = (char*)d_ws;
    float*    r2 = (float*)ws;                      // 128*10*640*4 = 3,276,800 B
    _Float16* dc = (_Float16*)(ws + 3276800);       // 128*55*4096*2 = 57,671,680 B

    bdc_pass1<<<dim3(NWG), dim3(256), 0, stream>>>(x, t, r2, dc);
    bdc_center<<<dim3(NWG), dim3(256), 0, stream>>>(dc, r2, out);
}

// Round 4
// 283.537 us; speedup vs baseline: 1.3350x; 1.0212x over previous
//
#include <hip/hip_runtime.h>
#include <cmath>

#define NB    128      // batches
#define DIM_  640
#define MM    100      // inner dim (K, unpadded)
#define XHR   128      // xh row length in halfs (zero-padded 100->128, 256 B rows)
#define LDK   136      // f16 staging LDS row stride in halfs (128 + 8 pad -> conflict-free frag reads)
#define TFS   68       // f32 direct-tile LDS stride (row-major), 2-way banks on scatter, 16B-aligned rows
#define TTS   66       // f32 mirror-tile LDS stride (col-major), ~2-way with XOR, 8B-aligned rows

#define NWG   (NB * 55)   // 7040 blocks; %8==0 -> simple XCD swizzle bijective
#define CPX   (NWG / 8)   // 880 = 16 whole batches per XCD

typedef _Float16 half8 __attribute__((ext_vector_type(8)));
typedef float f32x4 __attribute__((ext_vector_type(4)));

// XCD-aware bijective swizzle: a batch's 55 blocks (and 16 consecutive batches)
// stay on one XCD -> xh slice (164 KB/batch) + r2 live in that XCD's L2.
__device__ inline void decode_bp(int bid, int& b, int& p) {
    const int dec = (bid & 7) * CPX + (bid >> 3);
    b = dec / 55;
    p = dec - b * 55;
}

// ---------------------------------------------------------------- prep: x f32 -> xh f16 (padded rows), d[row] = sum f16^2
__global__ __launch_bounds__(256) void prep_xh(const float* __restrict__ x,
                                               _Float16* __restrict__ xh,
                                               float* __restrict__ d) {
    const int row  = blockIdx.x * 4 + (threadIdx.x >> 6);   // 1 row per wave
    const int lane = threadIdx.x & 63;
    const float* xr = x + (size_t)row * MM;
    float2 v = make_float2(0.f, 0.f);
    if (lane < 50) v = *(const float2*)(xr + 2 * lane);     // cols 2l, 2l+1 (l>=50 -> zero pad)
    const _Float16 h0 = (_Float16)v.x, h1 = (_Float16)v.y;
    const float a0 = (float)h0, a1 = (float)h1;
    float acc = a0 * a0 + a1 * a1;
    union { _Float16 h[2]; unsigned u; } pk;
    pk.h[0] = h0; pk.h[1] = h1;
    *(unsigned*)(xh + (size_t)row * XHR + 2 * lane) = pk.u; // 256 B/row contiguous per wave
    #pragma unroll
    for (int off = 32; off; off >>= 1) acc += __shfl_down(acc, off, 64);
    if (lane == 0) d[row] = acc;
}

// ---------------------------------------------------------------- stage 64-row f16 tile: pure 16 B copies, no cvt
__device__ inline void stage_xh(const _Float16* __restrict__ src,
                                _Float16* __restrict__ lds, int tid) {
    #pragma unroll
    for (int i = 0; i < 4; ++i) {
        const int idx = tid + i * 256;          // 0..1023
        const int row = idx >> 4;
        const int m   = idx & 15;               // 16 B chunk
        *(half8*)(lds + row * LDK + m * 8) = *(const half8*)(src + (size_t)row * XHR + m * 8);
    }
}

// ---------------------------------------------------------------- pass A: row/col sums only (no dcov store)
__global__ __launch_bounds__(256) void bdc_sums(
        const _Float16* __restrict__ xh, const float* __restrict__ d,
        const float* __restrict__ t, float* __restrict__ r2) {
    __shared__ alignas(16) _Float16 As[64 * LDK];
    __shared__ alignas(16) _Float16 Bs[64 * LDK];
    __shared__ float rowacc[64];
    __shared__ float colacc[64];

    int b, p;
    decode_bp(blockIdx.x, b, p);
    int it = 0, rem = p;
    while (rem >= 10 - it) { rem -= 10 - it; ++it; }
    const int jt = it + rem;
    const bool diag = (it == jt);

    const int tid = threadIdx.x;
    const int wave = tid >> 6;
    const int lane = tid & 63;
    const int l16  = lane & 15;
    const int quad = lane >> 4;
    const int rowhalf = wave >> 1;
    const int colhalf = wave & 1;

    if (tid < 64)  rowacc[tid] = 0.f;
    else if (tid < 128) colacc[tid - 64] = 0.f;

    const _Float16* xb = xh + (size_t)b * DIM_ * XHR;
    stage_xh(xb + (size_t)(it * 64) * XHR, As, tid);
    if (!diag) stage_xh(xb + (size_t)(jt * 64) * XHR, Bs, tid);

    const float expt = expf(t[0]);
    const float* db = d + b * DIM_;
    const int rbase = it * 64 + rowhalf * 32;
    const int cbase = jt * 64 + colhalf * 32;
    float dr[2][4];
    #pragma unroll
    for (int ti = 0; ti < 2; ++ti)
        #pragma unroll
        for (int r = 0; r < 4; ++r)
            dr[ti][r] = db[rbase + ti * 16 + quad * 4 + r];
    const float dcv[2] = { db[cbase + l16], db[cbase + 16 + l16] };

    __syncthreads();

    const _Float16* Bp = diag ? As : Bs;
    f32x4 acc[2][2] = {};
    #pragma unroll
    for (int kk = 0; kk < 4; ++kk) {
        const int k = kk * 32 + quad * 8;
        half8 a0 = *(const half8*)(&As[(rowhalf * 32 + l16) * LDK + k]);
        half8 a1 = *(const half8*)(&As[(rowhalf * 32 + 16 + l16) * LDK + k]);
        half8 b0 = *(const half8*)(&Bp[(colhalf * 32 + l16) * LDK + k]);
        half8 b1 = *(const half8*)(&Bp[(colhalf * 32 + 16 + l16) * LDK + k]);
        acc[0][0] = __builtin_amdgcn_mfma_f32_16x16x32_f16(a0, b0, acc[0][0], 0, 0, 0);
        acc[0][1] = __builtin_amdgcn_mfma_f32_16x16x32_f16(a0, b1, acc[0][1], 0, 0, 0);
        acc[1][0] = __builtin_amdgcn_mfma_f32_16x16x32_f16(a1, b0, acc[1][0], 0, 0, 0);
        acc[1][1] = __builtin_amdgcn_mfma_f32_16x16x32_f16(a1, b1, acc[1][1], 0, 0, 0);
    }

    float cp0 = 0.f, cp1 = 0.f;
    #pragma unroll
    for (int ti = 0; ti < 2; ++ti) {
        #pragma unroll
        for (int r = 0; r < 4; ++r) {
            const int gi = rbase + ti * 16 + quad * 4 + r;
            float raw0 = dr[ti][r] + dcv[0] - 2.0f * acc[ti][0][r];
            raw0 = (gi == cbase + l16) ? 1e-4f : fmaxf(raw0, 1e-4f);
            const float v0 = sqrtf(expt * raw0 + 1e-5f);
            float raw1 = dr[ti][r] + dcv[1] - 2.0f * acc[ti][1][r];
            raw1 = (gi == cbase + 16 + l16) ? 1e-4f : fmaxf(raw1, 1e-4f);
            const float v1 = sqrtf(expt * raw1 + 1e-5f);
            cp0 += v0; cp1 += v1;
            float s = v0 + v1;
            s += __shfl_xor(s, 1, 64);
            s += __shfl_xor(s, 2, 64);
            s += __shfl_xor(s, 4, 64);
            s += __shfl_xor(s, 8, 64);
            if (l16 == 0)
                atomicAdd(&rowacc[rowhalf * 32 + ti * 16 + quad * 4 + r], s);
        }
    }
    cp0 += __shfl_xor(cp0, 16, 64); cp0 += __shfl_xor(cp0, 32, 64);
    cp1 += __shfl_xor(cp1, 16, 64); cp1 += __shfl_xor(cp1, 32, 64);
    if (quad == 0) {
        atomicAdd(&colacc[colhalf * 32 + l16],      cp0);
        atomicAdd(&colacc[colhalf * 32 + 16 + l16], cp1);
    }

    __syncthreads();

    if (tid < 64) {   // per-slot partials: each (slot,row) written by exactly one block
        r2[((size_t)b * 10 + jt) * DIM_ + it * 64 + tid] = rowacc[tid];
        if (!diag)
            r2[((size_t)b * 10 + it) * DIM_ + jt * 64 + tid] = colacc[tid];
    }
}

// ---------------------------------------------------------------- pass B: recompute dcov, center, write direct + mirror
__global__ __launch_bounds__(256) void bdc_out(
        const _Float16* __restrict__ xh, const float* __restrict__ d,
        const float* __restrict__ t, const float* __restrict__ r2,
        float* __restrict__ out) {
    __shared__ alignas(16) char uni[35200];     // As+Bs (34816 B) unioned with Tf+Tt (34304 B)
    _Float16* As = (_Float16*)uni;
    _Float16* Bs = (_Float16*)(uni + 17408);
    float* Tf = (float*)uni;                    // [64][TFS] row-major direct tile
    float* Tt = (float*)(uni + 17408);          // [64][TTS] col-major mirror tile
    __shared__ float rm_s[DIM_];
    __shared__ float wred[4];

    int b, p;
    decode_bp(blockIdx.x, b, p);
    int it = 0, rem = p;
    while (rem >= 10 - it) { rem -= 10 - it; ++it; }
    const int jt = it + rem;
    const bool diag = (it == jt);

    const int tid  = threadIdx.x;
    const int wave = tid >> 6;
    const int lane = tid & 63;
    const int l16  = lane & 15;
    const int quad = lane >> 4;
    const int rowhalf = wave >> 1;
    const int colhalf = wave & 1;

    const _Float16* xb = xh + (size_t)b * DIM_ * XHR;
    stage_xh(xb + (size_t)(it * 64) * XHR, As, tid);
    if (!diag) stage_xh(xb + (size_t)(jt * 64) * XHR, Bs, tid);

    // row means + total from the slot table (overlaps staging latency)
    const float* rb = r2 + (size_t)b * 10 * DIM_;
    float tpart = 0.f;
    for (int i = tid; i < DIM_; i += 256) {
        float s = 0.f;
        #pragma unroll
        for (int ss = 0; ss < 10; ++ss) s += rb[ss * DIM_ + i];
        rm_s[i] = s * (1.0f / 640.0f);
        tpart += s;
    }
    #pragma unroll
    for (int off = 32; off; off >>= 1) tpart += __shfl_xor(tpart, off, 64);
    if (lane == 0) wred[wave] = tpart;

    const float expt = expf(t[0]);
    const float* db = d + b * DIM_;
    const int rbase = it * 64 + rowhalf * 32;
    const int cbase = jt * 64 + colhalf * 32;
    float dr[2][4];
    #pragma unroll
    for (int ti = 0; ti < 2; ++ti)
        #pragma unroll
        for (int r = 0; r < 4; ++r)
            dr[ti][r] = db[rbase + ti * 16 + quad * 4 + r];
    const float dcv[2] = { db[cbase + l16], db[cbase + 16 + l16] };

    __syncthreads();
    const float tot = (wred[0] + wred[1] + wred[2] + wred[3]) * (1.0f / 409600.0f);

    const _Float16* Bp = diag ? As : Bs;
    f32x4 acc[2][2] = {};
    #pragma unroll
    for (int kk = 0; kk < 4; ++kk) {
        const int k = kk * 32 + quad * 8;
        half8 a0 = *(const half8*)(&As[(rowhalf * 32 + l16) * LDK + k]);
        half8 a1 = *(const half8*)(&As[(rowhalf * 32 + 16 + l16) * LDK + k]);
        half8 b0 = *(const half8*)(&Bp[(colhalf * 32 + l16) * LDK + k]);
        half8 b1 = *(const half8*)(&Bp[(colhalf * 32 + 16 + l16) * LDK + k]);
        acc[0][0] = __builtin_amdgcn_mfma_f32_16x16x32_f16(a0, b0, acc[0][0], 0, 0, 0);
        acc[0][1] = __builtin_amdgcn_mfma_f32_16x16x32_f16(a0, b1, acc[0][1], 0, 0, 0);
        acc[1][0] = __builtin_amdgcn_mfma_f32_16x16x32_f16(a1, b0, acc[1][0], 0, 0, 0);
        acc[1][1] = __builtin_amdgcn_mfma_f32_16x16x32_f16(a1, b1, acc[1][1], 0, 0, 0);
    }

    // centered values in registers
    float o[2][4][2];
    #pragma unroll
    for (int ti = 0; ti < 2; ++ti)
        #pragma unroll
        for (int r = 0; r < 4; ++r) {
            const int gi = rbase + ti * 16 + quad * 4 + r;
            const float rowterm = tot - rm_s[gi];
            #pragma unroll
            for (int tj = 0; tj < 2; ++tj) {
                const int gj = cbase + tj * 16 + l16;
                float raw = dr[ti][r] + dcv[tj] - 2.0f * acc[ti][tj][r];
                raw = (gi == gj) ? 1e-4f : fmaxf(raw, 1e-4f);
                o[ti][r][tj] = sqrtf(expt * raw + 1e-5f) + rowterm - rm_s[gj];
            }
        }

    __syncthreads();   // As/Bs + rm_s reads done -> Tf/Tt may overwrite As/Bs

    #pragma unroll
    for (int ti = 0; ti < 2; ++ti)
        #pragma unroll
        for (int r = 0; r < 4; ++r) {
            const int rowl = rowhalf * 32 + ti * 16 + quad * 4 + r;
            #pragma unroll
            for (int tj = 0; tj < 2; ++tj) {
                const int coll = colhalf * 32 + tj * 16 + l16;
                Tf[rowl * TFS + coll] = o[ti][r][tj];                        // 2-way banks
                if (!diag)
                    Tt[coll * TTS + (rowl ^ ((l16 & 3) << 2))] = o[ti][r][tj]; // ~2-way via XOR
            }
        }

    __syncthreads();

    float* ob = out + (size_t)b * DIM_ * DIM_;
    #pragma unroll
    for (int k4 = 0; k4 < 4; ++k4) {            // direct tile: vec4 row stores
        const int w  = tid + k4 * 256;
        const int rr = w >> 4;
        const int c4 = (w & 15) * 4;
        const f32x4 v = *(const f32x4*)(&Tf[rr * TFS + c4]);
        *(f32x4*)(ob + (size_t)(it * 64 + rr) * DIM_ + jt * 64 + c4) = v;
    }
    if (!diag) {
        #pragma unroll
        for (int k4 = 0; k4 < 4; ++k4) {        // mirror tile: un-XOR reads, vec4 stores
            const int w  = tid + k4 * 256;
            const int rr = w >> 4;
            const int c4 = (w & 15) * 4;
            const int cc = c4 ^ ((rr & 3) << 2);
            const float2 p0 = *(const float2*)(&Tt[rr * TTS + cc]);
            const float2 p1 = *(const float2*)(&Tt[rr * TTS + cc + 2]);
            const f32x4 v = { p0.x, p0.y, p1.x, p1.y };
            *(f32x4*)(ob + (size_t)(jt * 64 + rr) * DIM_ + it * 64 + c4) = v;
        }
    }
}

// ---------------------------------------------------------------- launch
extern "C" void kernel_launch(void* const* d_in, const int* in_sizes, int n_in,
                              void* d_out, int out_size, void* d_ws, size_t ws_size,
                              hipStream_t stream) {
    const float* x = (const float*)d_in[0];
    const float* t = (const float*)d_in[1];
    float* out = (float*)d_out;

    char* ws = (char*)d_ws;
    _Float16* xh = (_Float16*)ws;                   // 128*640*128*2 = 20,971,520 B
    float*    d  = (float*)(ws + 20971520);         // 327,680 B
    float*    r2 = (float*)(ws + 20971520 + 327680);// 3,276,800 B

    prep_xh<<<dim3(NB * DIM_ / 4), dim3(256), 0, stream>>>(x, xh, d);
    bdc_sums<<<dim3(NWG), dim3(256), 0, stream>>>(xh, d, t, r2);
    bdc_out<<<dim3(NWG), dim3(256), 0, stream>>>(xh, d, t, r2, out);
}

// Round 5
// 275.473 us; speedup vs baseline: 1.3741x; 1.0293x over previous
//
#include <hip/hip_runtime.h>
#include <cmath>

#define NB    128      // batches
#define DIM_  640
#define MM    100      // inner dim (K, unpadded)
#define XHR   128      // xh row length in halfs (zero-padded 100->128, 256 B rows)
#define LDK   136      // f16 staging LDS row stride in halfs (128 + 8 pad -> conflict-free frag reads)
#define TFS   68       // f32 direct-tile LDS stride (row-major)
#define TTS   66       // f32 mirror-tile LDS stride (col-major)
#define RSS   34       // rsum row stride in floats (32 slots + 2 pad -> 2-way banks, 8B aligned)
#define CSS   10       // csum row stride in floats (8 slots + 2 pad)

#define NWG   (NB * 55)   // 7040 blocks; %8==0 -> simple XCD swizzle bijective
#define CPX   (NWG / 8)   // 880 = 16 whole batches per XCD

typedef _Float16 half8 __attribute__((ext_vector_type(8)));
typedef float f32x4 __attribute__((ext_vector_type(4)));

// XCD-aware bijective swizzle: a batch's 55 blocks (and 16 consecutive batches)
// stay on one XCD -> xh slice + rm/tot accumulators live in that XCD's L2.
__device__ inline void decode_bp(int bid, int& b, int& p) {
    const int dec = (bid & 7) * CPX + (bid >> 3);
    b = dec / 55;
    p = dec - b * 55;
}

// ---------------------------------------------------------------- prep: x f32 -> xh f16 (padded rows), d[row] = sum f16^2
// also zeroes rm (81920 f) + tot (128 f, contiguous after rm)
__global__ __launch_bounds__(256) void prep_xh(const float* __restrict__ x,
                                               _Float16* __restrict__ xh,
                                               float* __restrict__ d,
                                               float* __restrict__ rmz) {
    if (blockIdx.x < 321) {
        const int z = blockIdx.x * 256 + threadIdx.x;
        if (z < 82048) rmz[z] = 0.f;
    }
    const int row  = blockIdx.x * 4 + (threadIdx.x >> 6);   // 1 row per wave
    const int lane = threadIdx.x & 63;
    const float* xr = x + (size_t)row * MM;
    float2 v = make_float2(0.f, 0.f);
    if (lane < 50) v = *(const float2*)(xr + 2 * lane);     // cols 2l, 2l+1 (l>=50 -> zero pad)
    const _Float16 h0 = (_Float16)v.x, h1 = (_Float16)v.y;
    const float a0 = (float)h0, a1 = (float)h1;
    float acc = a0 * a0 + a1 * a1;
    union { _Float16 h[2]; unsigned u; } pk;
    pk.h[0] = h0; pk.h[1] = h1;
    *(unsigned*)(xh + (size_t)row * XHR + 2 * lane) = pk.u;
    #pragma unroll
    for (int off = 32; off; off >>= 1) acc += __shfl_down(acc, off, 64);
    if (lane == 0) d[row] = acc;
}

// ---------------------------------------------------------------- stage 64-row f16 tile: pure 16 B copies
__device__ inline void stage_xh(const _Float16* __restrict__ src,
                                _Float16* __restrict__ lds, int tid) {
    #pragma unroll
    for (int i = 0; i < 4; ++i) {
        const int idx = tid + i * 256;          // 0..1023
        const int row = idx >> 4;
        const int m   = idx & 15;               // 16 B chunk
        *(half8*)(lds + row * LDK + m * 8) = *(const half8*)(src + (size_t)row * XHR + m * 8);
    }
}

// ---------------------------------------------------------------- pass A: row/col sums via LDS scatter-reduce
__global__ __launch_bounds__(256) void bdc_sums(
        const _Float16* __restrict__ xh, const float* __restrict__ d,
        const float* __restrict__ t, float* __restrict__ rm,
        float* __restrict__ tot) {
    __shared__ alignas(16) _Float16 As[64 * LDK];
    __shared__ alignas(16) _Float16 Bs[64 * LDK];
    float* rsum = (float*)As;                    // [64][RSS] aliases As (dead after MFMA)
    float* csum = (float*)As + 64 * RSS;         // [64][CSS], total 11264 B <= 17408 B

    int b, p;
    decode_bp(blockIdx.x, b, p);
    int it = 0, rem = p;
    while (rem >= 10 - it) { rem -= 10 - it; ++it; }
    const int jt = it + rem;
    const bool diag = (it == jt);

    const int tid = threadIdx.x;
    const int wave = tid >> 6;
    const int lane = tid & 63;
    const int l16  = lane & 15;
    const int quad = lane >> 4;
    const int rowhalf = wave >> 1;
    const int colhalf = wave & 1;

    const _Float16* xb = xh + (size_t)b * DIM_ * XHR;
    stage_xh(xb + (size_t)(it * 64) * XHR, As, tid);
    if (!diag) stage_xh(xb + (size_t)(jt * 64) * XHR, Bs, tid);

    const float expt = expf(t[0]);
    const float* db = d + b * DIM_;
    const int rbase = it * 64 + rowhalf * 32;
    const int cbase = jt * 64 + colhalf * 32;
    float dr[2][4];
    #pragma unroll
    for (int ti = 0; ti < 2; ++ti)
        #pragma unroll
        for (int r = 0; r < 4; ++r)
            dr[ti][r] = db[rbase + ti * 16 + quad * 4 + r];
    const float dcv[2] = { db[cbase + l16], db[cbase + 16 + l16] };

    __syncthreads();

    const _Float16* Bp = diag ? As : Bs;
    f32x4 acc[2][2] = {};
    #pragma unroll
    for (int kk = 0; kk < 4; ++kk) {
        const int k = kk * 32 + quad * 8;
        half8 a0 = *(const half8*)(&As[(rowhalf * 32 + l16) * LDK + k]);
        half8 a1 = *(const half8*)(&As[(rowhalf * 32 + 16 + l16) * LDK + k]);
        half8 b0 = *(const half8*)(&Bp[(colhalf * 32 + l16) * LDK + k]);
        half8 b1 = *(const half8*)(&Bp[(colhalf * 32 + 16 + l16) * LDK + k]);
        acc[0][0] = __builtin_amdgcn_mfma_f32_16x16x32_f16(a0, b0, acc[0][0], 0, 0, 0);
        acc[0][1] = __builtin_amdgcn_mfma_f32_16x16x32_f16(a0, b1, acc[0][1], 0, 0, 0);
        acc[1][0] = __builtin_amdgcn_mfma_f32_16x16x32_f16(a1, b0, acc[1][0], 0, 0, 0);
        acc[1][1] = __builtin_amdgcn_mfma_f32_16x16x32_f16(a1, b1, acc[1][1], 0, 0, 0);
    }

    // dcov values -> per-thread partials (no cross-lane ops here)
    float s2[2][4];
    float cp0 = 0.f, cp1 = 0.f;
    #pragma unroll
    for (int ti = 0; ti < 2; ++ti) {
        #pragma unroll
        for (int r = 0; r < 4; ++r) {
            const int gi = rbase + ti * 16 + quad * 4 + r;
            float raw0 = dr[ti][r] + dcv[0] - 2.0f * acc[ti][0][r];
            raw0 = (gi == cbase + l16) ? 1e-4f : fmaxf(raw0, 1e-4f);
            const float v0 = sqrtf(expt * raw0 + 1e-5f);
            float raw1 = dr[ti][r] + dcv[1] - 2.0f * acc[ti][1][r];
            raw1 = (gi == cbase + 16 + l16) ? 1e-4f : fmaxf(raw1, 1e-4f);
            const float v1 = sqrtf(expt * raw1 + 1e-5f);
            s2[ti][r] = v0 + v1;
            cp0 += v0; cp1 += v1;
        }
    }

    __syncthreads();   // all frag reads done -> rsum/csum may overwrite As

    #pragma unroll
    for (int ti = 0; ti < 2; ++ti)
        #pragma unroll
        for (int r = 0; r < 4; ++r)
            rsum[(rowhalf * 32 + ti * 16 + quad * 4 + r) * RSS + colhalf * 16 + l16] = s2[ti][r];
    csum[(colhalf * 32 + l16) * CSS + rowhalf * 4 + quad]      = cp0;
    csum[(colhalf * 32 + 16 + l16) * CSS + rowhalf * 4 + quad] = cp1;

    __syncthreads();

    if (tid < 64) {                              // row totals (wave 0): contiguous float2 reads
        float rt = 0.f;
        const float2* rp = (const float2*)(rsum + tid * RSS);
        #pragma unroll
        for (int k = 0; k < 16; ++k) { const float2 u = rp[k]; rt += u.x + u.y; }
        atomicAdd(&rm[b * DIM_ + it * 64 + tid], rt);
        float ts = rt;                           // block's tile total -> tot
        #pragma unroll
        for (int off = 1; off < 64; off <<= 1) ts += __shfl_xor(ts, off, 64);
        if (tid == 0) atomicAdd(&tot[b], diag ? ts : 2.0f * ts);
    } else if (tid < 128 && !diag) {             // col totals -> mirrored rows (wave 1)
        const int c = tid - 64;
        float ct = 0.f;
        #pragma unroll
        for (int s = 0; s < 8; ++s) ct += csum[c * CSS + s];
        atomicAdd(&rm[b * DIM_ + jt * 64 + c], ct);
    }
}

// ---------------------------------------------------------------- pass B: recompute dcov, center, write direct + mirror (nt stores)
__global__ __launch_bounds__(256) void bdc_out(
        const _Float16* __restrict__ xh, const float* __restrict__ d,
        const float* __restrict__ t, const float* __restrict__ rm,
        const float* __restrict__ tot_g, float* __restrict__ out) {
    __shared__ alignas(16) char uni[35200];     // As+Bs (34816 B) unioned with Tf+Tt (34304 B)
    _Float16* As = (_Float16*)uni;
    _Float16* Bs = (_Float16*)(uni + 17408);
    float* Tf = (float*)uni;                    // [64][TFS] row-major direct tile
    float* Tt = (float*)(uni + 17408);          // [64][TTS] col-major mirror tile
    __shared__ float rm_s[DIM_];

    int b, p;
    decode_bp(blockIdx.x, b, p);
    int it = 0, rem = p;
    while (rem >= 10 - it) { rem -= 10 - it; ++it; }
    const int jt = it + rem;
    const bool diag = (it == jt);

    const int tid  = threadIdx.x;
    const int wave = tid >> 6;
    const int lane = tid & 63;
    const int l16  = lane & 15;
    const int quad = lane >> 4;
    const int rowhalf = wave >> 1;
    const int colhalf = wave & 1;

    const _Float16* xb = xh + (size_t)b * DIM_ * XHR;
    stage_xh(xb + (size_t)(it * 64) * XHR, As, tid);
    if (!diag) stage_xh(xb + (size_t)(jt * 64) * XHR, Bs, tid);

    // row-mean sums are already reduced in rm -> 3 loads/thread (L2-hot, same XCD)
    const float* rmg = rm + (size_t)b * DIM_;
    for (int i = tid; i < DIM_; i += 256) rm_s[i] = rmg[i] * (1.0f / 640.0f);
    const float tot = tot_g[b] * (1.0f / 409600.0f);

    const float expt = expf(t[0]);
    const float* db = d + b * DIM_;
    const int rbase = it * 64 + rowhalf * 32;
    const int cbase = jt * 64 + colhalf * 32;
    float dr[2][4];
    #pragma unroll
    for (int ti = 0; ti < 2; ++ti)
        #pragma unroll
        for (int r = 0; r < 4; ++r)
            dr[ti][r] = db[rbase + ti * 16 + quad * 4 + r];
    const float dcv[2] = { db[cbase + l16], db[cbase + 16 + l16] };

    __syncthreads();

    const _Float16* Bp = diag ? As : Bs;
    f32x4 acc[2][2] = {};
    #pragma unroll
    for (int kk = 0; kk < 4; ++kk) {
        const int k = kk * 32 + quad * 8;
        half8 a0 = *(const half8*)(&As[(rowhalf * 32 + l16) * LDK + k]);
        half8 a1 = *(const half8*)(&As[(rowhalf * 32 + 16 + l16) * LDK + k]);
        half8 b0 = *(const half8*)(&Bp[(colhalf * 32 + l16) * LDK + k]);
        half8 b1 = *(const half8*)(&Bp[(colhalf * 32 + 16 + l16) * LDK + k]);
        acc[0][0] = __builtin_amdgcn_mfma_f32_16x16x32_f16(a0, b0, acc[0][0], 0, 0, 0);
        acc[0][1] = __builtin_amdgcn_mfma_f32_16x16x32_f16(a0, b1, acc[0][1], 0, 0, 0);
        acc[1][0] = __builtin_amdgcn_mfma_f32_16x16x32_f16(a1, b0, acc[1][0], 0, 0, 0);
        acc[1][1] = __builtin_amdgcn_mfma_f32_16x16x32_f16(a1, b1, acc[1][1], 0, 0, 0);
    }

    // centered values in registers
    float o[2][4][2];
    #pragma unroll
    for (int ti = 0; ti < 2; ++ti)
        #pragma unroll
        for (int r = 0; r < 4; ++r) {
            const int gi = rbase + ti * 16 + quad * 4 + r;
            const float rowterm = tot - rm_s[gi];
            #pragma unroll
            for (int tj = 0; tj < 2; ++tj) {
                const int gj = cbase + tj * 16 + l16;
                float raw = dr[ti][r] + dcv[tj] - 2.0f * acc[ti][tj][r];
                raw = (gi == gj) ? 1e-4f : fmaxf(raw, 1e-4f);
                o[ti][r][tj] = sqrtf(expt * raw + 1e-5f) + rowterm - rm_s[gj];
            }
        }

    __syncthreads();   // As/Bs + rm_s reads done -> Tf/Tt may overwrite As/Bs

    #pragma unroll
    for (int ti = 0; ti < 2; ++ti)
        #pragma unroll
        for (int r = 0; r < 4; ++r) {
            const int rowl = rowhalf * 32 + ti * 16 + quad * 4 + r;
            #pragma unroll
            for (int tj = 0; tj < 2; ++tj) {
                const int coll = colhalf * 32 + tj * 16 + l16;
                Tf[rowl * TFS + coll] = o[ti][r][tj];
                if (!diag)
                    Tt[coll * TTS + (rowl ^ ((l16 & 3) << 2))] = o[ti][r][tj];
            }
        }

    __syncthreads();

    float* ob = out + (size_t)b * DIM_ * DIM_;
    #pragma unroll
    for (int k4 = 0; k4 < 4; ++k4) {            // direct tile: nt vec4 row stores
        const int w  = tid + k4 * 256;
        const int rr = w >> 4;
        const int c4 = (w & 15) * 4;
        const f32x4 v = *(const f32x4*)(&Tf[rr * TFS + c4]);
        __builtin_nontemporal_store(v, (f32x4*)(ob + (size_t)(it * 64 + rr) * DIM_ + jt * 64 + c4));
    }
    if (!diag) {
        #pragma unroll
        for (int k4 = 0; k4 < 4; ++k4) {        // mirror tile: un-XOR reads, nt vec4 stores
            const int w  = tid + k4 * 256;
            const int rr = w >> 4;
            const int c4 = (w & 15) * 4;
            const int cc = c4 ^ ((rr & 3) << 2);
            const float2 p0 = *(const float2*)(&Tt[rr * TTS + cc]);
            const float2 p1 = *(const float2*)(&Tt[rr * TTS + cc + 2]);
            const f32x4 v = { p0.x, p0.y, p1.x, p1.y };
            __builtin_nontemporal_store(v, (f32x4*)(ob + (size_t)(jt * 64 + rr) * DIM_ + it * 64 + c4));
        }
    }
}

// ---------------------------------------------------------------- launch
extern "C" void kernel_launch(void* const* d_in, const int* in_sizes, int n_in,
                              void* d_out, int out_size, void* d_ws, size_t ws_size,
                              hipStream_t stream) {
    const float* x = (const float*)d_in[0];
    const float* t = (const float*)d_in[1];
    float* out = (float*)d_out;

    char* ws = (char*)d_ws;
    _Float16* xh = (_Float16*)ws;                        // 20,971,520 B
    float*    d  = (float*)(ws + 20971520);              // 327,680 B
    float*    rm = (float*)(ws + 20971520 + 327680);     // 327,680 B (sum accumulators)
    float*    tot= (float*)(ws + 20971520 + 2 * 327680); // 512 B, contiguous after rm

    prep_xh<<<dim3(NB * DIM_ / 4), dim3(256), 0, stream>>>(x, xh, d, rm);
    bdc_sums<<<dim3(NWG), dim3(256), 0, stream>>>(xh, d, t, rm, tot);
    bdc_out<<<dim3(NWG), dim3(256), 0, stream>>>(xh, d, t, rm, tot, out);
}

// Round 7
// 274.816 us; speedup vs baseline: 1.3773x; 1.0024x over previous
//
#include <hip/hip_runtime.h>
#include <cmath>

#define NB    128      // batches
#define DIM_  640
#define MM    100      // inner dim (K, unpadded)
#define XHR   128      // xh row length in halfs (zero-padded 100->128, 256 B rows)
#define LDK   136      // f16 staging LDS row stride in halfs (128 + 8 pad -> conflict-free frag reads)
#define TFS   68       // f32 direct-tile LDS stride (row-major)
#define TTS   66       // f32 mirror-tile LDS stride (col-major)
#define RSS   34       // rsum row stride in floats (32 slots + 2 pad -> 2-way banks, 8B aligned)
#define CSS   10       // csum row stride in floats (8 slots + 2 pad)

#define NWG   (NB * 55)   // 7040 blocks; %8==0 -> simple XCD swizzle bijective
#define CPX   (NWG / 8)   // 880 = 16 whole batches per XCD

typedef _Float16 half8 __attribute__((ext_vector_type(8)));
typedef float f32x4 __attribute__((ext_vector_type(4)));

// fast hw sqrt: v_sqrt_f32 (1-2 ulp; tolerance is 7.8e-3)
#define FSQRT(x) __builtin_amdgcn_sqrtf(x)

// XCD-aware bijective swizzle: a batch's 55 blocks (and 16 consecutive batches)
// stay on one XCD -> xh slice + rm/tot accumulators live in that XCD's L2.
__device__ inline void decode_bp(int bid, int& b, int& p) {
    const int dec = (bid & 7) * CPX + (bid >> 3);
    b = dec / 55;
    p = dec - b * 55;
}

// ---------------------------------------------------------------- prep: x f32 -> xh f16 (padded rows), d[row] = sum f16^2
// also zeroes rm (81920 f) + tot (128 f, contiguous after rm)
__global__ __launch_bounds__(256) void prep_xh(const float* __restrict__ x,
                                               _Float16* __restrict__ xh,
                                               float* __restrict__ d,
                                               float* __restrict__ rmz) {
    if (blockIdx.x < 321) {
        const int z = blockIdx.x * 256 + threadIdx.x;
        if (z < 82048) rmz[z] = 0.f;
    }
    const int row  = blockIdx.x * 4 + (threadIdx.x >> 6);   // 1 row per wave
    const int lane = threadIdx.x & 63;
    const float* xr = x + (size_t)row * MM;
    float2 v = make_float2(0.f, 0.f);
    if (lane < 50) v = *(const float2*)(xr + 2 * lane);     // cols 2l, 2l+1 (l>=50 -> zero pad)
    const _Float16 h0 = (_Float16)v.x, h1 = (_Float16)v.y;
    const float a0 = (float)h0, a1 = (float)h1;
    float acc = a0 * a0 + a1 * a1;
    union { _Float16 h[2]; unsigned u; } pk;
    pk.h[0] = h0; pk.h[1] = h1;
    *(unsigned*)(xh + (size_t)row * XHR + 2 * lane) = pk.u;
    #pragma unroll
    for (int off = 32; off; off >>= 1) acc += __shfl_down(acc, off, 64);
    if (lane == 0) d[row] = acc;
}

// ---------------------------------------------------------------- stage 64-row f16 tile: pure 16 B copies
__device__ inline void stage_xh(const _Float16* __restrict__ src,
                                _Float16* __restrict__ lds, int tid) {
    #pragma unroll
    for (int i = 0; i < 4; ++i) {
        const int idx = tid + i * 256;          // 0..1023
        const int row = idx >> 4;
        const int m   = idx & 15;               // 16 B chunk
        *(half8*)(lds + row * LDK + m * 8) = *(const half8*)(src + (size_t)row * XHR + m * 8);
    }
}

// ---------------------------------------------------------------- pass A: row/col sums via LDS scatter-reduce
__global__ __launch_bounds__(256, 4) void bdc_sums(
        const _Float16* __restrict__ xh, const float* __restrict__ d,
        const float* __restrict__ t, float* __restrict__ rm,
        float* __restrict__ tot) {
    __shared__ alignas(16) _Float16 As[64 * LDK];
    __shared__ alignas(16) _Float16 Bs[64 * LDK];
    float* rsum = (float*)As;                    // [64][RSS] aliases As (dead after MFMA)
    float* csum = (float*)As + 64 * RSS;         // [64][CSS], total 11264 B <= 17408 B

    int b, p;
    decode_bp(blockIdx.x, b, p);
    int it = 0, rem = p;
    while (rem >= 10 - it) { rem -= 10 - it; ++it; }
    const int jt = it + rem;
    const bool diag = (it == jt);

    const int tid = threadIdx.x;
    const int wave = tid >> 6;
    const int lane = tid & 63;
    const int l16  = lane & 15;
    const int quad = lane >> 4;
    const int rowhalf = wave >> 1;
    const int colhalf = wave & 1;

    const _Float16* xb = xh + (size_t)b * DIM_ * XHR;
    stage_xh(xb + (size_t)(it * 64) * XHR, As, tid);
    if (!diag) stage_xh(xb + (size_t)(jt * 64) * XHR, Bs, tid);

    const float expt = __expf(t[0]);
    const float* db = d + b * DIM_;
    const int rbase = it * 64 + rowhalf * 32;
    const int cbase = jt * 64 + colhalf * 32;
    float dr[2][4];
    #pragma unroll
    for (int ti = 0; ti < 2; ++ti)
        #pragma unroll
        for (int r = 0; r < 4; ++r)
            dr[ti][r] = db[rbase + ti * 16 + quad * 4 + r];
    const float dcv[2] = { db[cbase + l16], db[cbase + 16 + l16] };

    __syncthreads();

    const _Float16* Bp = diag ? As : Bs;
    f32x4 acc[2][2] = {};
    #pragma unroll
    for (int kk = 0; kk < 4; ++kk) {
        const int k = kk * 32 + quad * 8;
        half8 a0 = *(const half8*)(&As[(rowhalf * 32 + l16) * LDK + k]);
        half8 a1 = *(const half8*)(&As[(rowhalf * 32 + 16 + l16) * LDK + k]);
        half8 b0 = *(const half8*)(&Bp[(colhalf * 32 + l16) * LDK + k]);
        half8 b1 = *(const half8*)(&Bp[(colhalf * 32 + 16 + l16) * LDK + k]);
        acc[0][0] = __builtin_amdgcn_mfma_f32_16x16x32_f16(a0, b0, acc[0][0], 0, 0, 0);
        acc[0][1] = __builtin_amdgcn_mfma_f32_16x16x32_f16(a0, b1, acc[0][1], 0, 0, 0);
        acc[1][0] = __builtin_amdgcn_mfma_f32_16x16x32_f16(a1, b0, acc[1][0], 0, 0, 0);
        acc[1][1] = __builtin_amdgcn_mfma_f32_16x16x32_f16(a1, b1, acc[1][1], 0, 0, 0);
    }

    // dcov values -> per-thread partials
    float s2[2][4];
    float cp0 = 0.f, cp1 = 0.f;
    #pragma unroll
    for (int ti = 0; ti < 2; ++ti) {
        #pragma unroll
        for (int r = 0; r < 4; ++r) {
            const int gi = rbase + ti * 16 + quad * 4 + r;
            float raw0 = dr[ti][r] + dcv[0] - 2.0f * acc[ti][0][r];
            raw0 = (gi == cbase + l16) ? 1e-4f : fmaxf(raw0, 1e-4f);
            const float v0 = FSQRT(expt * raw0 + 1e-5f);
            float raw1 = dr[ti][r] + dcv[1] - 2.0f * acc[ti][1][r];
            raw1 = (gi == cbase + 16 + l16) ? 1e-4f : fmaxf(raw1, 1e-4f);
            const float v1 = FSQRT(expt * raw1 + 1e-5f);
            s2[ti][r] = v0 + v1;
            cp0 += v0; cp1 += v1;
        }
    }

    __syncthreads();   // all frag reads done -> rsum/csum may overwrite As

    #pragma unroll
    for (int ti = 0; ti < 2; ++ti)
        #pragma unroll
        for (int r = 0; r < 4; ++r)
            rsum[(rowhalf * 32 + ti * 16 + quad * 4 + r) * RSS + colhalf * 16 + l16] = s2[ti][r];
    csum[(colhalf * 32 + l16) * CSS + rowhalf * 4 + quad]      = cp0;
    csum[(colhalf * 32 + 16 + l16) * CSS + rowhalf * 4 + quad] = cp1;

    __syncthreads();

    if (tid < 64) {                              // row totals (wave 0): contiguous float2 reads
        float rt = 0.f;
        const float2* rp = (const float2*)(rsum + tid * RSS);
        #pragma unroll
        for (int k = 0; k < 16; ++k) { const float2 u = rp[k]; rt += u.x + u.y; }
        atomicAdd(&rm[b * DIM_ + it * 64 + tid], rt);
        float ts = rt;                           // block's tile total -> tot
        #pragma unroll
        for (int off = 1; off < 64; off <<= 1) ts += __shfl_xor(ts, off, 64);
        if (tid == 0) atomicAdd(&tot[b], diag ? ts : 2.0f * ts);
    } else if (tid < 128 && !diag) {             // col totals -> mirrored rows (wave 1)
        const int c = tid - 64;
        float ct = 0.f;
        #pragma unroll
        for (int s = 0; s < 8; ++s) ct += csum[c * CSS + s];
        atomicAdd(&rm[b * DIM_ + jt * 64 + c], ct);
    }
}

// ---------------------------------------------------------------- pass B: recompute dcov, center, write direct + mirror (nt stores)
__global__ __launch_bounds__(256) void bdc_out(
        const _Float16* __restrict__ xh, const float* __restrict__ d,
        const float* __restrict__ t, const float* __restrict__ rm,
        const float* __restrict__ tot_g, float* __restrict__ out) {
    __shared__ alignas(16) char uni[35200];     // As+Bs (34816 B) unioned with Tf+Tt (34304 B)
    _Float16* As = (_Float16*)uni;
    _Float16* Bs = (_Float16*)(uni + 17408);
    float* Tf = (float*)uni;                    // [64][TFS] row-major direct tile
    float* Tt = (float*)(uni + 17408);          // [64][TTS] col-major mirror tile
    __shared__ float rm_i[64];                  // only the 128 means this tile needs
    __shared__ float rm_j[64];

    int b, p;
    decode_bp(blockIdx.x, b, p);
    int it = 0, rem = p;
    while (rem >= 10 - it) { rem -= 10 - it; ++it; }
    const int jt = it + rem;
    const bool diag = (it == jt);

    const int tid  = threadIdx.x;
    const int wave = tid >> 6;
    const int lane = tid & 63;
    const int l16  = lane & 15;
    const int quad = lane >> 4;
    const int rowhalf = wave >> 1;
    const int colhalf = wave & 1;

    const _Float16* xb = xh + (size_t)b * DIM_ * XHR;
    stage_xh(xb + (size_t)(it * 64) * XHR, As, tid);
    if (!diag) stage_xh(xb + (size_t)(jt * 64) * XHR, Bs, tid);

    // only the 64 row-means and 64 col-means this tile touches (L2-hot, same XCD)
    const float* rmg = rm + (size_t)b * DIM_;
    if (tid < 64)       rm_i[tid]      = rmg[it * 64 + tid]        * (1.0f / 640.0f);
    else if (tid < 128) rm_j[tid - 64] = rmg[jt * 64 + (tid - 64)] * (1.0f / 640.0f);
    const float tot = tot_g[b] * (1.0f / 409600.0f);

    const float expt = __expf(t[0]);
    const float* db = d + b * DIM_;
    const int rbase = it * 64 + rowhalf * 32;
    const int cbase = jt * 64 + colhalf * 32;
    float dr[2][4];
    #pragma unroll
    for (int ti = 0; ti < 2; ++ti)
        #pragma unroll
        for (int r = 0; r < 4; ++r)
            dr[ti][r] = db[rbase + ti * 16 + quad * 4 + r];
    const float dcv[2] = { db[cbase + l16], db[cbase + 16 + l16] };

    __syncthreads();

    const _Float16* Bp = diag ? As : Bs;
    f32x4 acc[2][2] = {};
    #pragma unroll
    for (int kk = 0; kk < 4; ++kk) {
        const int k = kk * 32 + quad * 8;
        half8 a0 = *(const half8*)(&As[(rowhalf * 32 + l16) * LDK + k]);
        half8 a1 = *(const half8*)(&As[(rowhalf * 32 + 16 + l16) * LDK + k]);
        half8 b0 = *(const half8*)(&Bp[(colhalf * 32 + l16) * LDK + k]);
        half8 b1 = *(const half8*)(&Bp[(colhalf * 32 + 16 + l16) * LDK + k]);
        acc[0][0] = __builtin_amdgcn_mfma_f32_16x16x32_f16(a0, b0, acc[0][0], 0, 0, 0);
        acc[0][1] = __builtin_amdgcn_mfma_f32_16x16x32_f16(a0, b1, acc[0][1], 0, 0, 0);
        acc[1][0] = __builtin_amdgcn_mfma_f32_16x16x32_f16(a1, b0, acc[1][0], 0, 0, 0);
        acc[1][1] = __builtin_amdgcn_mfma_f32_16x16x32_f16(a1, b1, acc[1][1], 0, 0, 0);
    }

    // centered values in registers (fast hw sqrt)
    float o[2][4][2];
    #pragma unroll
    for (int ti = 0; ti < 2; ++ti)
        #pragma unroll
        for (int r = 0; r < 4; ++r) {
            const int rowl = rowhalf * 32 + ti * 16 + quad * 4 + r;
            const int gi = it * 64 + rowl;
            const float rowterm = tot - rm_i[rowl];
            #pragma unroll
            for (int tj = 0; tj < 2; ++tj) {
                const int coll = colhalf * 32 + tj * 16 + l16;
                const int gj = jt * 64 + coll;
                float raw = dr[ti][r] + dcv[tj] - 2.0f * acc[ti][tj][r];
                raw = (gi == gj) ? 1e-4f : fmaxf(raw, 1e-4f);
                o[ti][r][tj] = FSQRT(expt * raw + 1e-5f) + rowterm - rm_j[coll];
            }
        }

    __syncthreads();   // As/Bs + rm reads done -> Tf/Tt may overwrite As/Bs

    #pragma unroll
    for (int ti = 0; ti < 2; ++ti)
        #pragma unroll
        for (int r = 0; r < 4; ++r) {
            const int rowl = rowhalf * 32 + ti * 16 + quad * 4 + r;
            #pragma unroll
            for (int tj = 0; tj < 2; ++tj) {
                const int coll = colhalf * 32 + tj * 16 + l16;
                Tf[rowl * TFS + coll] = o[ti][r][tj];
                if (!diag)
                    Tt[coll * TTS + (rowl ^ ((l16 & 3) << 2))] = o[ti][r][tj];
            }
        }

    __syncthreads();

    float* ob = out + (size_t)b * DIM_ * DIM_;
    #pragma unroll
    for (int k4 = 0; k4 < 4; ++k4) {            // direct tile: nt vec4 row stores
        const int w  = tid + k4 * 256;
        const int rr = w >> 4;
        const int c4 = (w & 15) * 4;
        const f32x4 v = *(const f32x4*)(&Tf[rr * TFS + c4]);
        __builtin_nontemporal_store(v, (f32x4*)(ob + (size_t)(it * 64 + rr) * DIM_ + jt * 64 + c4));
    }
    if (!diag) {
        #pragma unroll
        for (int k4 = 0; k4 < 4; ++k4) {        // mirror tile: un-XOR reads, nt vec4 stores
            const int w  = tid + k4 * 256;
            const int rr = w >> 4;
            const int c4 = (w & 15) * 4;
            const int cc = c4 ^ ((rr & 3) << 2);
            const float2 p0 = *(const float2*)(&Tt[rr * TTS + cc]);
            const float2 p1 = *(const float2*)(&Tt[rr * TTS + cc + 2]);
            const f32x4 v = { p0.x, p0.y, p1.x, p1.y };
            __builtin_nontemporal_store(v, (f32x4*)(ob + (size_t)(jt * 64 + rr) * DIM_ + it * 64 + c4));
        }
    }
}

// ---------------------------------------------------------------- launch
extern "C" void kernel_launch(void* const* d_in, const int* in_sizes, int n_in,
                              void* d_out, int out_size, void* d_ws, size_t ws_size,
                              hipStream_t stream) {
    const float* x = (const float*)d_in[0];
    const float* t = (const float*)d_in[1];
    float* out = (float*)d_out;

    char* ws = (char*)d_ws;
    _Float16* xh = (_Float16*)ws;                        // 20,971,520 B
    float*    d  = (float*)(ws + 20971520);              // 327,680 B
    float*    rm = (float*)(ws + 20971520 + 327680);     // 327,680 B (sum accumulators)
    float*    tot= (float*)(ws + 20971520 + 2 * 327680); // 512 B, contiguous after rm

    prep_xh<<<dim3(NB * DIM_ / 4), dim3(256), 0, stream>>>(x, xh, d, rm);
    bdc_sums<<<dim3(NWG), dim3(256), 0, stream>>>(xh, d, t, rm, tot);
    bdc_out<<<dim3(NWG), dim3(256), 0, stream>>>(xh, d, t, rm, tot, out);
}